// Round 8
// baseline (14.669 us; speedup 1.0000x reference)
//
#include <hip/hip_runtime.h>

constexpr int NPIX = 360 * 640;            // 230400 = 900 * 256 exactly
constexpr int NSQ = 8, NSAMP = 10;
constexpr float FARV = 1.5f;
constexpr float SHARPV = 1000.0f;
constexpr float TAU2 = 100.0f * 1.44269504f;   // TAU * log2(e)
constexpr float DT9 = 2.0f / 9.0f;
constexpr float TBAND = 25.0f;   // |t|>25 -> occ within 2^-25 of {0,1}: ev = {1,0} exactly enough

struct SQT {
  float A[9];      // R * diag(1/s):  w_j = sum_i A[i][j] * rd_i
  float tc[3];
  float ie1, ie2, c21, Kq;
  float thr;       // 1.02 * exact circumscribed radius^2
  float vis0;      // vis at near point (beta=0, pixel-independent)
};

// log2 f, f = (y0^(1/e2)+y1^(1/e2))^(e2/e1) + y2^(1/e1), y = q^2+1e-12
// 7 trans ops (5 log + 2 exp2)
__device__ __forceinline__ float lf_eval(float q0, float q1, float q2,
                                         float ie1, float ie2, float c21) {
  const float y0 = fmaf(q0, q0, 1e-12f);
  const float y1 = fmaf(q1, q1, 1e-12f);
  const float y2 = fmaf(q2, q2, 1e-12f);
  const float la = ie2 * __builtin_amdgcn_logf(y0);
  const float lb = ie2 * __builtin_amdgcn_logf(y1);
  const float lc = ie1 * __builtin_amdgcn_logf(y2);
  const float mab = fmaxf(la, lb), nab = fminf(la, lb);
  const float lab = mab + __builtin_amdgcn_logf(1.0f + __builtin_amdgcn_exp2f(nab - mab));
  const float lg = c21 * lab;
  const float mf = fmaxf(lg, lc), nf = fminf(lg, lc);
  return mf + __builtin_amdgcn_logf(1.0f + __builtin_amdgcn_exp2f(nf - mf));
}

__global__ __launch_bounds__(256) void depth_kernel(
    const float* __restrict__ poses, const float* __restrict__ params,
    const float* __restrict__ rays_d, const float* __restrict__ rays_o,
    float* __restrict__ out)
{
  __shared__ SQT sq[NSQ];
  const int tid = threadIdx.x;

  if (tid < NSQ) {
    const int n = tid;
    const float* P = poses + n * 16;
    const float* par = params + n * 5;
    const float is0 = 1.0f / par[0], is1 = 1.0f / par[1], is2 = 1.0f / par[2];
    const float e1 = par[3], e2 = par[4];
    SQT q;
    q.A[0] = P[0] * is0;  q.A[1] = P[1] * is1;  q.A[2] = P[2]  * is2;
    q.A[3] = P[4] * is0;  q.A[4] = P[5] * is1;  q.A[5] = P[6]  * is2;
    q.A[6] = P[8] * is0;  q.A[7] = P[9] * is1;  q.A[8] = P[10] * is2;
    const float d0 = rays_o[0] - P[3], d1 = rays_o[1] - P[7], d2 = rays_o[2] - P[11];
    q.tc[0] = q.A[0] * d0 + q.A[3] * d1 + q.A[6] * d2;
    q.tc[1] = q.A[1] * d0 + q.A[4] * d1 + q.A[7] * d2;
    q.tc[2] = q.A[2] * d0 + q.A[5] * d1 + q.A[8] * d2;
    q.ie1 = 1.0f / e1; q.ie2 = 1.0f / e2; q.c21 = e2 * q.ie1;
    q.Kq = SHARPV * e1;
    // exact circumscribed radius^2 of F=1 surface (squared-coord frame)
    const float c = __builtin_amdgcn_exp2f(1.0f - e2);
    const float V1 = (e1 < 1.0f) ? __builtin_amdgcn_exp2f(1.0f - e1) : 1.0f;
    float V2;
    if (e1 < 0.999f) {
      const float cp = __builtin_amdgcn_exp2f((1.0f - e2) / (1.0f - e1));
      V2 = __builtin_amdgcn_exp2f((1.0f - e1) * __builtin_amdgcn_logf(1.0f + cp));
    } else {
      V2 = fmaxf(c, 1.0f);
    }
    q.thr = 1.02f * fmaxf(V1, V2);
    const float lf0 = lf_eval(q.tc[0], q.tc[1], q.tc[2], q.ie1, q.ie2, q.c21);
    const float occ0 = __builtin_amdgcn_rcpf(1.0f + __builtin_amdgcn_exp2f(q.Kq * lf0));
    q.vis0 = __builtin_amdgcn_exp2f(-TAU2 * occ0);
    sq[n] = q;
  }
  __syncthreads();

  const int pix = blockIdx.x * blockDim.x + tid;
  const float rd0 = rays_d[pix * 3 + 0];
  const float rd1 = rays_d[pix * 3 + 1];
  const float rd2 = rays_d[pix * 3 + 2];

  float m = FARV;

  for (int n = 0; n < NSQ; n++) {
    const SQT& q = sq[n];   // broadcast LDS reads (conflict-free)
    const float w0 = q.A[0] * rd0 + q.A[3] * rd1 + q.A[6] * rd2;
    const float w1 = q.A[1] * rd0 + q.A[4] * rd1 + q.A[7] * rd2;
    const float w2 = q.A[2] * rd0 + q.A[5] * rd1 + q.A[8] * rd2;
    const float tc0 = q.tc[0], tc1 = q.tc[1], tc2 = q.tc[2];

    const float lam2 = w0 * w0 + w1 * w1 + w2 * w2;
    const float dd = tc0 * w0 + tc1 * w1 + tc2 * w2;
    const float pb = fabsf(dd) * __builtin_amdgcn_rcpf(lam2);  // closest approach
    const float ce0 = fmaf(pb, w0, tc0);
    const float ce1 = fmaf(pb, w1, tc1);
    const float ce2 = fmaf(pb, w2, tc2);
    const float dist2 = ce0 * ce0 + ce1 * ce1 + ce2 * ce2;
    const bool hit = dist2 < q.thr;
    if (!__any(hit)) continue;          // wave-uniform skip

    const float hb = sqrtf(fmaxf(3.0f - dist2, 1e-12f)) * rsqrtf(lam2);
    const float ie1 = q.ie1, ie2 = q.ie2, c21 = q.c21, Kq = q.Kq;
    const float step = hb * DT9;
    const float sw0 = step * w0, sw1 = step * w1, sw2 = step * w2;

    // ---- phase 1: 11 independent lf evals (trans-pipe ILP) ----
    float lf[NSAMP + 1];
    {
      float a0 = fmaf(pb - hb, w0, tc0);
      float a1 = fmaf(pb - hb, w1, tc1);
      float a2 = fmaf(pb - hb, w2, tc2);
#pragma unroll
      for (int k = 0; k < NSAMP; k++) {
        lf[k] = lf_eval(a0, a1, a2, ie1, ie2, c21);
        a0 += sw0; a1 += sw1; a2 += sw2;
      }
      lf[NSAMP] = lf_eval(fmaf(FARV, w0, tc0), fmaf(FARV, w1, tc1),
                          fmaf(FARV, w2, tc2), ie1, ie2, c21);
    }

    // ---- phase 2: ev + vis chain; sigmoid tail only if a lane is in-band ----
    float v = q.vis0;
    float depth = 0.0f, mid = 0.0f;
#pragma unroll
    for (int k = 0; k <= NSAMP; k++) {
      const float t = Kq * lf[k];
      const bool inband = hit && (fabsf(t) < TBAND);
      float ev;
      if (__any(inband)) {
        const float occ = __builtin_amdgcn_rcpf(1.0f + __builtin_amdgcn_exp2f(t));
        ev = __builtin_amdgcn_exp2f(-TAU2 * occ);
      } else {
        // occ saturates: ev = 1 (outside) or 2^-144 ~= 0 (inside)
        ev = (t < 0.0f) ? 0.0f : 1.0f;
      }
      const float vn = v * ev;
      if (k == 0) {
        depth = (v + vn) * fabsf(pb - hb);         // near segment
      } else if (k < NSAMP) {
        mid += v + vn;                             // uniform interior
      } else {
        depth += mid * step;
        depth += (v + vn) * fabsf(FARV - pb - hb); // far segment
      }
      v = vn;
    }
    depth *= 0.5f;

    m = fminf(m, hit ? depth : FARV);
  }

  out[pix] = m;
}

extern "C" void kernel_launch(void* const* d_in, const int* in_sizes, int n_in,
                              void* d_out, int out_size, void* d_ws, size_t ws_size,
                              hipStream_t stream) {
  const float* poses  = (const float*)d_in[0];
  const float* params = (const float*)d_in[1];
  const float* rays_d = (const float*)d_in[2];
  const float* rays_o = (const float*)d_in[3];

  depth_kernel<<<NPIX / 256, 256, 0, stream>>>(
      poses, params, rays_d, rays_o, (float*)d_out);
}

// Round 9
// 12.666 us; speedup vs baseline: 1.1581x; 1.1581x over previous
//
#include <hip/hip_runtime.h>

constexpr int NPIX = 360 * 640;            // 230400 = 3600 * 64 exactly
constexpr int NSQ = 8, NSAMP = 10;
constexpr float FARV = 1.5f;
constexpr float SHARPV = 1000.0f;
constexpr float TAU2 = 100.0f * 1.44269504f;   // TAU * log2(e)
constexpr float DT9 = 2.0f / 9.0f;

struct SQT {
  float A[9];      // R * diag(1/s):  w_j = sum_i A[i][j] * rd_i
  float tc[3];
  float ie1, ie2, c21, Kq;
  float thr;       // 1.02 * exact circumscribed radius^2
  float vis0;      // vis at near point (beta=0, pixel-independent)
};

// log2 f, f = (y0^(1/e2)+y1^(1/e2))^(e2/e1) + y2^(1/e1), y = q^2+1e-12
__device__ __forceinline__ float lf_eval(float q0, float q1, float q2,
                                         float ie1, float ie2, float c21) {
  const float y0 = fmaf(q0, q0, 1e-12f);
  const float y1 = fmaf(q1, q1, 1e-12f);
  const float y2 = fmaf(q2, q2, 1e-12f);
  const float la = ie2 * __builtin_amdgcn_logf(y0);
  const float lb = ie2 * __builtin_amdgcn_logf(y1);
  const float lc = ie1 * __builtin_amdgcn_logf(y2);
  const float mab = fmaxf(la, lb), nab = fminf(la, lb);
  const float lab = mab + __builtin_amdgcn_logf(1.0f + __builtin_amdgcn_exp2f(nab - mab));
  const float lg = c21 * lab;
  const float mf = fmaxf(lg, lc), nf = fminf(lg, lc);
  return mf + __builtin_amdgcn_logf(1.0f + __builtin_amdgcn_exp2f(nf - mf));
}

// block = 1 wave (64 threads): fine-grained dynamic load balance across CUs
__global__ __launch_bounds__(64) void depth_kernel(
    const float* __restrict__ poses, const float* __restrict__ params,
    const float* __restrict__ rays_d, const float* __restrict__ rays_o,
    float* __restrict__ out)
{
  __shared__ SQT sq[NSQ];
  const int tid = threadIdx.x;

  if (tid < NSQ) {
    const int n = tid;
    const float* P = poses + n * 16;
    const float* par = params + n * 5;
    const float is0 = 1.0f / par[0], is1 = 1.0f / par[1], is2 = 1.0f / par[2];
    const float e1 = par[3], e2 = par[4];
    SQT q;
    q.A[0] = P[0] * is0;  q.A[1] = P[1] * is1;  q.A[2] = P[2]  * is2;
    q.A[3] = P[4] * is0;  q.A[4] = P[5] * is1;  q.A[5] = P[6]  * is2;
    q.A[6] = P[8] * is0;  q.A[7] = P[9] * is1;  q.A[8] = P[10] * is2;
    const float d0 = rays_o[0] - P[3], d1 = rays_o[1] - P[7], d2 = rays_o[2] - P[11];
    q.tc[0] = q.A[0] * d0 + q.A[3] * d1 + q.A[6] * d2;
    q.tc[1] = q.A[1] * d0 + q.A[4] * d1 + q.A[7] * d2;
    q.tc[2] = q.A[2] * d0 + q.A[5] * d1 + q.A[8] * d2;
    q.ie1 = 1.0f / e1; q.ie2 = 1.0f / e2; q.c21 = e2 * q.ie1;
    q.Kq = SHARPV * e1;
    // exact circumscribed radius^2 of F=1 surface (squared-coord frame)
    const float c = __builtin_amdgcn_exp2f(1.0f - e2);
    const float V1 = (e1 < 1.0f) ? __builtin_amdgcn_exp2f(1.0f - e1) : 1.0f;
    float V2;
    if (e1 < 0.999f) {
      const float cp = __builtin_amdgcn_exp2f((1.0f - e2) / (1.0f - e1));
      V2 = __builtin_amdgcn_exp2f((1.0f - e1) * __builtin_amdgcn_logf(1.0f + cp));
    } else {
      V2 = fmaxf(c, 1.0f);
    }
    q.thr = 1.02f * fmaxf(V1, V2);
    const float lf0 = lf_eval(q.tc[0], q.tc[1], q.tc[2], q.ie1, q.ie2, q.c21);
    const float occ0 = __builtin_amdgcn_rcpf(1.0f + __builtin_amdgcn_exp2f(q.Kq * lf0));
    q.vis0 = __builtin_amdgcn_exp2f(-TAU2 * occ0);
    sq[n] = q;
  }
  __syncthreads();

  const int pix = blockIdx.x * 64 + tid;
  const float rd0 = rays_d[pix * 3 + 0];
  const float rd1 = rays_d[pix * 3 + 1];
  const float rd2 = rays_d[pix * 3 + 2];

  float m = FARV;

  for (int n = 0; n < NSQ; n++) {
    const SQT& q = sq[n];   // broadcast LDS reads (conflict-free)
    const float w0 = q.A[0] * rd0 + q.A[3] * rd1 + q.A[6] * rd2;
    const float w1 = q.A[1] * rd0 + q.A[4] * rd1 + q.A[7] * rd2;
    const float w2 = q.A[2] * rd0 + q.A[5] * rd1 + q.A[8] * rd2;
    const float tc0 = q.tc[0], tc1 = q.tc[1], tc2 = q.tc[2];

    const float lam2 = w0 * w0 + w1 * w1 + w2 * w2;
    const float dd = tc0 * w0 + tc1 * w1 + tc2 * w2;
    const float pb = fabsf(dd) * __builtin_amdgcn_rcpf(lam2);  // closest approach
    const float ce0 = fmaf(pb, w0, tc0);
    const float ce1 = fmaf(pb, w1, tc1);
    const float ce2 = fmaf(pb, w2, tc2);
    const float dist2 = ce0 * ce0 + ce1 * ce1 + ce2 * ce2;
    const bool hit = dist2 < q.thr;
    if (!__any(hit)) continue;          // wave-uniform skip

    const float hb = sqrtf(fmaxf(3.0f - dist2, 1e-12f)) * rsqrtf(lam2);
    const float ie1 = q.ie1, ie2 = q.ie2, c21 = q.c21, Kq = q.Kq;

    float ev[NSAMP + 1];
#pragma unroll
    for (int k = 0; k <= NSAMP; k++) {
      const float b = (k < NSAMP) ? fmaf(fmaf((float)k, DT9, -1.0f), hb, pb) : FARV;
      const float lf = lf_eval(fmaf(b, w0, tc0), fmaf(b, w1, tc1), fmaf(b, w2, tc2),
                               ie1, ie2, c21);
      const float occ = __builtin_amdgcn_rcpf(1.0f + __builtin_amdgcn_exp2f(Kq * lf));
      ev[k] = __builtin_amdgcn_exp2f(-TAU2 * occ);
    }

    float v = q.vis0;
    float vn = v * ev[0];
    float depth = (v + vn) * fabsf(pb - hb);      // near segment
    v = vn;
    float mid = 0.0f;
#pragma unroll
    for (int k = 1; k < NSAMP; k++) { vn = v * ev[k]; mid += v + vn; v = vn; }
    depth += mid * (hb * DT9);                     // uniform interior spacing
    vn = v * ev[NSAMP];
    depth += (v + vn) * fabsf(FARV - pb - hb);     // far segment
    depth *= 0.5f;

    m = fminf(m, hit ? depth : FARV);
  }

  out[pix] = m;
}

extern "C" void kernel_launch(void* const* d_in, const int* in_sizes, int n_in,
                              void* d_out, int out_size, void* d_ws, size_t ws_size,
                              hipStream_t stream) {
  const float* poses  = (const float*)d_in[0];
  const float* params = (const float*)d_in[1];
  const float* rays_d = (const float*)d_in[2];
  const float* rays_o = (const float*)d_in[3];

  depth_kernel<<<NPIX / 64, 64, 0, stream>>>(
      poses, params, rays_d, rays_o, (float*)d_out);
}